// Round 1
// baseline (9.620 us; speedup 1.0000x reference)
//
#include <hip/hip_runtime.h>
#include <hip/hip_bf16.h>

// mean over the NxN matrix of (x[j]-x[i])^2 collapses to 2*(E[x^2] - E[x]^2).
// Single-block double-precision reduction over the 16384-element input.

__global__ __launch_bounds__(1024)
void EditLoss_55525337203377_kernel(const float* __restrict__ x,
                                    float* __restrict__ out, int n) {
    double s = 0.0, s2 = 0.0;
    const float4* x4 = reinterpret_cast<const float4*>(x);
    const int n4 = n >> 2;  // n is a multiple of 4 (16384)
    for (int i = threadIdx.x; i < n4; i += blockDim.x) {
        float4 v = x4[i];
        s  += (double)v.x + (double)v.y + (double)v.z + (double)v.w;
        s2 += (double)v.x * v.x + (double)v.y * v.y
            + (double)v.z * v.z + (double)v.w * v.w;
    }

    // Wave-64 shuffle reduction.
    #pragma unroll
    for (int off = 32; off > 0; off >>= 1) {
        s  += __shfl_down(s, off, 64);
        s2 += __shfl_down(s2, off, 64);
    }

    __shared__ double ls[16], ls2[16];
    const int lane = threadIdx.x & 63;
    const int wid  = threadIdx.x >> 6;
    if (lane == 0) { ls[wid] = s; ls2[wid] = s2; }
    __syncthreads();

    if (threadIdx.x == 0) {
        double S = 0.0, S2 = 0.0;
        const int nw = blockDim.x >> 6;
        for (int w = 0; w < nw; ++w) { S += ls[w]; S2 += ls2[w]; }
        const double dn = (double)n;
        const double mean = S / dn;
        out[0] = (float)(2.0 * (S2 / dn - mean * mean));
    }
}

extern "C" void kernel_launch(void* const* d_in, const int* in_sizes, int n_in,
                              void* d_out, int out_size, void* d_ws, size_t ws_size,
                              hipStream_t stream) {
    const float* x = (const float*)d_in[0];
    float* out = (float*)d_out;
    const int n = in_sizes[0];  // 16384
    EditLoss_55525337203377_kernel<<<1, 1024, 0, stream>>>(x, out, n);
}